// Round 9
// baseline (2906.666 us; speedup 1.0000x reference)
//
#include <hip/hip_runtime.h>
#include <cstddef>

// Problem constants (reference: B=8, S=512, E=128, H=512, ENC=128)
#define BB 8
#define SS 512
#define EE 128
#define HH 512
#define ENC 128

// ---------------------------------------------------------------------------
// Bit-exact emulation of XLA CPU's EmitTanh (verified bitwise in rounds 6/7).
// All ops rn, NON-fused. __f*_rn intrinsics block compiler contraction.
// ---------------------------------------------------------------------------
__device__ __forceinline__ float xla_tanhf(float x) {
    const float cx = fminf(fmaxf(x, -9.0f), 9.0f);
    const float x2 = __fmul_rn(cx, cx);
    float p = -2.76076847742355e-16f;
    p = __fadd_rn(__fmul_rn(p, x2), 2.00018790482477e-13f);
    p = __fadd_rn(__fmul_rn(p, x2), -8.60467152213735e-11f);
    p = __fadd_rn(__fmul_rn(p, x2), 5.12229709037114e-08f);
    p = __fadd_rn(__fmul_rn(p, x2), 1.48572235717979e-05f);
    p = __fadd_rn(__fmul_rn(p, x2), 6.37261928875436e-04f);
    p = __fadd_rn(__fmul_rn(p, x2), 4.89352455891786e-03f);
    const float num = __fmul_rn(cx, p);
    float q = 1.19825839466702e-06f;
    q = __fadd_rn(__fmul_rn(q, x2), 1.18534705686654e-04f);
    q = __fadd_rn(__fmul_rn(q, x2), 2.26843463243900e-03f);
    q = __fadd_rn(__fmul_rn(q, x2), 4.89352518554385e-03f);
    const float r = __fdiv_rn(num, q);
    return (fabsf(x) < 0.0004f) ? x : r;
}

// Map a packed chunk-row m -> global action row:
//   b = m >> chsh (CH = chm1+1), global row = b*SS + i0 + (m & chm1)
__device__ __forceinline__ int arow_map(int m, int chm1, int chsh, int i0) {
    return ((m >> chsh) * SS) + i0 + (m & chm1);
}

// ---------------------------------------------------------------------------
// Tiled GEMM, bitwise-preserving XLA-CPU dot semantics (VERIFIED r6/r7 —
// scalar v_mul/v_add only; do NOT substitute packed/fused ops, r8 regressed):
//   C[m,n] = act( seq_{k asc} add(mul(A[row(m),k], B[n,k])) + bias[n] )
// One accumulator per output element; k0 tiles ascend, inner k ascends.
// Tiles BM=BN=128, BK=16; 256 threads; 8x8 outputs/thread; LDS-staged.
// ---------------------------------------------------------------------------
template <int ACT, int MAPROW>
__global__ __launch_bounds__(256) void gemm_nt(const float* __restrict__ A,
                                               const float* __restrict__ Bm,
                                               const float* __restrict__ bias,
                                               float* __restrict__ C,
                                               int N, int K,
                                               int chm1, int chsh, int i0) {
    __shared__ float As[16][128];
    __shared__ float Bs[16][128];

    const int tid = threadIdx.x;
    const int tx = tid & 15;   // n-direction (8 cols each)
    const int ty = tid >> 4;   // m-direction (8 rows each)
    const int n0 = blockIdx.x * 128;
    const int m0 = blockIdx.y * 128;

    const int lr = tid >> 2;          // 0..63 (row within tile)
    const int lc = (tid & 3) << 2;    // 0,4,8,12 (col within K-tile)

    const int ga0 = MAPROW ? arow_map(m0 + lr, chm1, chsh, i0) : (m0 + lr);
    const int ga1 = MAPROW ? arow_map(m0 + lr + 64, chm1, chsh, i0) : (m0 + lr + 64);

    float acc[8][8];
#pragma unroll
    for (int i = 0; i < 8; ++i)
#pragma unroll
        for (int j = 0; j < 8; ++j) acc[i][j] = 0.f;

    for (int k0 = 0; k0 < K; k0 += 16) {
        const float4 a0 = *(const float4*)(A + (size_t)ga0 * K + (k0 + lc));
        const float4 a1 = *(const float4*)(A + (size_t)ga1 * K + (k0 + lc));
        const float4 b0 = *(const float4*)(Bm + (size_t)(n0 + lr) * K + (k0 + lc));
        const float4 b1 = *(const float4*)(Bm + (size_t)(n0 + lr + 64) * K + (k0 + lc));

        __syncthreads();  // previous iteration's compute done before overwrite

        As[lc + 0][lr] = a0.x; As[lc + 1][lr] = a0.y;
        As[lc + 2][lr] = a0.z; As[lc + 3][lr] = a0.w;
        As[lc + 0][lr + 64] = a1.x; As[lc + 1][lr + 64] = a1.y;
        As[lc + 2][lr + 64] = a1.z; As[lc + 3][lr + 64] = a1.w;
        Bs[lc + 0][lr] = b0.x; Bs[lc + 1][lr] = b0.y;
        Bs[lc + 2][lr] = b0.z; Bs[lc + 3][lr] = b0.w;
        Bs[lc + 0][lr + 64] = b1.x; Bs[lc + 1][lr + 64] = b1.y;
        Bs[lc + 2][lr + 64] = b1.z; Bs[lc + 3][lr + 64] = b1.w;

        __syncthreads();

#pragma unroll
        for (int k = 0; k < 16; ++k) {   // ascending k within tile
            const float4 av0 = *(const float4*)&As[k][ty * 8];
            const float4 av1 = *(const float4*)&As[k][ty * 8 + 4];
            const float4 bv0 = *(const float4*)&Bs[k][tx * 8];
            const float4 bv1 = *(const float4*)&Bs[k][tx * 8 + 4];
            const float a[8] = {av0.x, av0.y, av0.z, av0.w, av1.x, av1.y, av1.z, av1.w};
            const float b[8] = {bv0.x, bv0.y, bv0.z, bv0.w, bv1.x, bv1.y, bv1.z, bv1.w};
#pragma unroll
            for (int i = 0; i < 8; ++i)
#pragma unroll
                for (int j = 0; j < 8; ++j)
                    acc[i][j] = __fadd_rn(acc[i][j], __fmul_rn(a[i], b[j]));
        }
    }

    // epilogue: + bias (after full k-chain), optional XLA tanh, float4 store
#pragma unroll
    for (int i = 0; i < 8; ++i) {
        const int m = m0 + ty * 8 + i;
        float v[8];
#pragma unroll
        for (int j = 0; j < 8; ++j) {
            const int n = n0 + tx * 8 + j;
            v[j] = __fadd_rn(acc[i][j], bias[n]);
            if (ACT) v[j] = xla_tanhf(v[j]);
        }
        float4* dst = (float4*)(C + (size_t)m * N + (n0 + tx * 8));
        dst[0] = make_float4(v[0], v[1], v[2], v[3]);
        dst[1] = make_float4(v[4], v[5], v[6], v[7]);
    }
}

// ---------------------------------------------------------------------------
// Sequential attractor scan, register-batched W loads. Arithmetic chain is
// op-for-op identical to the r6/r7 verified version (ascending d, non-fused
// __fmul_rn/__fadd_rn, one accumulator) — only memory scheduling differs.
// One block per batch, 128 threads (thread = output coord e).
// ---------------------------------------------------------------------------
__global__ __launch_bounds__(128, 1) void scan_kernel(const float* __restrict__ Wa,
                                                      const float* __restrict__ e0,
                                                      float* __restrict__ et_state,
                                                      float* __restrict__ out,
                                                      int i0, int CH) {
    const int b = blockIdx.x;
    const int e = threadIdx.x;  // 0..127

    __shared__ float et_lds[128];  // LDS offset 0 => 16B-aligned for float4

    if (i0 == 0) {
        const float v = e0[e];
        et_lds[e] = v;
        out[(size_t)b * SS * ENC + e] = v;
    } else {
        et_lds[e] = et_state[b * 128 + e];
    }
    __syncthreads();

    const int start = (i0 == 0) ? 1 : 0;
    for (int ii = start; ii < CH; ++ii) {
        const int i = i0 + ii;
        const float* W = Wa + ((size_t)b * CH + ii) * (ENC * ENC);

        // batch all 128 W loads (independent, coalesced across lanes)
        float w[128];
#pragma unroll
        for (int d = 0; d < 128; ++d) w[d] = W[d * ENC + e];

        // dependency chain: ascending d, non-fused (bitwise contract)
        float sum = 0.f;
#pragma unroll
        for (int q = 0; q < 32; ++q) {
            const float4 t = *(const float4*)&et_lds[q * 4];
            sum = __fadd_rn(sum, __fmul_rn(t.x, w[q * 4 + 0]));
            sum = __fadd_rn(sum, __fmul_rn(t.y, w[q * 4 + 1]));
            sum = __fadd_rn(sum, __fmul_rn(t.z, w[q * 4 + 2]));
            sum = __fadd_rn(sum, __fmul_rn(t.w, w[q * 4 + 3]));
        }
        const float v = fminf(fmaxf(sum, -5.f), 5.f);  // jnp.clip
        out[((size_t)b * SS + i) * ENC + e] = v;
        __syncthreads();   // all chain reads of et_lds done before overwrite
        et_lds[e] = v;
        __syncthreads();   // new et visible to all
    }
    et_state[b * 128 + e] = et_lds[e];
}

// ---------------------------------------------------------------------------
extern "C" void kernel_launch(void* const* d_in, const int* in_sizes, int n_in,
                              void* d_out, int out_size, void* d_ws, size_t ws_size,
                              hipStream_t stream) {
    const float* A  = (const float*)d_in[0];  // (B,S,E)   = (8,512,128) fp32
    const float* W1 = (const float*)d_in[1];  // (H,E)     = (512,128)  fp32
    const float* b1 = (const float*)d_in[2];  // (H,)      fp32
    const float* W2 = (const float*)d_in[3];  // (ENC*ENC,H) = (16384,512) fp32
    const float* b2 = (const float*)d_in[4];  // (ENC*ENC,) fp32
    const float* e0 = (const float*)d_in[5];  // (1,ENC)   fp32
    float* out = (float*)d_out;               // (B,S,ENC) fp32

    // Pick the largest chunk CH (steps) whose fp32 workspace fits ws_size.
    // ws layout: [et_state 4KB][hidden_c Mc*512 f32][Wa_c Mc*16384 f32], Mc=8*CH
    int CH = 16;  // minimum (Mc=128, one M-tile); needs ~8.7 MB
    for (int c = 512; c >= 16; c >>= 1) {
        const size_t Mc = (size_t)BB * c;
        const size_t need = 4096 + Mc * HH * sizeof(float) +
                            Mc * (size_t)(ENC * ENC) * sizeof(float);
        if (need <= ws_size) { CH = c; break; }
    }
    const int Mc = BB * CH;
    int chsh = 0;
    while ((1 << chsh) < CH) ++chsh;
    const int chm1 = CH - 1;

    float* et_state = (float*)d_ws;
    float* hidden   = (float*)((char*)d_ws + 4096);
    float* Wa       = hidden + (size_t)Mc * HH;

    for (int i0 = 0; i0 < SS; i0 += CH) {
        // GEMM1: hidden_c = tanh(A[chunk rows] @ W1^T + b1)  [Mc x 512, K=128]
        dim3 g1(HH / 128, Mc / 128);
        gemm_nt<1, 1><<<g1, 256, 0, stream>>>(A, W1, b1, hidden, HH, EE,
                                              chm1, chsh, i0);
        // GEMM2: Wa_c = hidden_c @ W2^T + b2   [Mc x 16384, K=512]
        dim3 g2((ENC * ENC) / 128, Mc / 128);
        gemm_nt<0, 0><<<g2, 256, 0, stream>>>(hidden, W2, b2, Wa, ENC * ENC, HH,
                                              0, 0, 0);
        // scan this chunk (one workgroup per batch; fp32 state in ws)
        scan_kernel<<<BB, 128, 0, stream>>>(Wa, e0, et_state, out, i0, CH);
    }
}

// Round 11
// 2043.933 us; speedup vs baseline: 1.4221x; 1.4221x over previous
//
#include <hip/hip_runtime.h>
#include <cstddef>

// Problem constants (reference: B=8, S=512, E=128, H=512, ENC=128)
#define BB 8
#define SS 512
#define EE 128
#define HH 512
#define ENC 128

// ---------------------------------------------------------------------------
// Bit-exact emulation of XLA CPU's EmitTanh (verified bitwise r6/r7/r9).
// All ops rn, NON-fused. __f*_rn intrinsics block compiler contraction.
// NOTE (r8): packed v_pk_* fp32 is NOT bit-identical on gfx950 — scalar only.
// ---------------------------------------------------------------------------
__device__ __forceinline__ float xla_tanhf(float x) {
    const float cx = fminf(fmaxf(x, -9.0f), 9.0f);
    const float x2 = __fmul_rn(cx, cx);
    float p = -2.76076847742355e-16f;
    p = __fadd_rn(__fmul_rn(p, x2), 2.00018790482477e-13f);
    p = __fadd_rn(__fmul_rn(p, x2), -8.60467152213735e-11f);
    p = __fadd_rn(__fmul_rn(p, x2), 5.12229709037114e-08f);
    p = __fadd_rn(__fmul_rn(p, x2), 1.48572235717979e-05f);
    p = __fadd_rn(__fmul_rn(p, x2), 6.37261928875436e-04f);
    p = __fadd_rn(__fmul_rn(p, x2), 4.89352455891786e-03f);
    const float num = __fmul_rn(cx, p);
    float q = 1.19825839466702e-06f;
    q = __fadd_rn(__fmul_rn(q, x2), 1.18534705686654e-04f);
    q = __fadd_rn(__fmul_rn(q, x2), 2.26843463243900e-03f);
    q = __fadd_rn(__fmul_rn(q, x2), 4.89352518554385e-03f);
    const float r = __fdiv_rn(num, q);
    return (fabsf(x) < 0.0004f) ? x : r;
}

// Map a packed chunk-row m -> global action row:
//   b = m >> chsh (CH = chm1+1), global row = b*SS + i0 + (m & chm1)
__device__ __forceinline__ int arow_map(int m, int chm1, int chsh, int i0) {
    return ((m >> chsh) * SS) + i0 + (m & chm1);
}

// ---------------------------------------------------------------------------
// Tiled GEMM, bitwise-preserving XLA-CPU dot semantics (VERIFIED r6/r7/r9,
// passed graph-replay twice — scalar v_mul/v_add only; r8's packed ops
// regressed). At the scalar-VALU floor for GEMM2 (~874 us). DO NOT TOUCH.
// ---------------------------------------------------------------------------
template <int ACT, int MAPROW>
__global__ __launch_bounds__(256) void gemm_nt(const float* __restrict__ A,
                                               const float* __restrict__ Bm,
                                               const float* __restrict__ bias,
                                               float* __restrict__ C,
                                               int N, int K,
                                               int chm1, int chsh, int i0) {
    __shared__ float As[16][128];
    __shared__ float Bs[16][128];

    const int tid = threadIdx.x;
    const int tx = tid & 15;   // n-direction (8 cols each)
    const int ty = tid >> 4;   // m-direction (8 rows each)
    const int n0 = blockIdx.x * 128;
    const int m0 = blockIdx.y * 128;

    const int lr = tid >> 2;          // 0..63 (row within tile)
    const int lc = (tid & 3) << 2;    // 0,4,8,12 (col within K-tile)

    const int ga0 = MAPROW ? arow_map(m0 + lr, chm1, chsh, i0) : (m0 + lr);
    const int ga1 = MAPROW ? arow_map(m0 + lr + 64, chm1, chsh, i0) : (m0 + lr + 64);

    float acc[8][8];
#pragma unroll
    for (int i = 0; i < 8; ++i)
#pragma unroll
        for (int j = 0; j < 8; ++j) acc[i][j] = 0.f;

    for (int k0 = 0; k0 < K; k0 += 16) {
        const float4 a0 = *(const float4*)(A + (size_t)ga0 * K + (k0 + lc));
        const float4 a1 = *(const float4*)(A + (size_t)ga1 * K + (k0 + lc));
        const float4 b0 = *(const float4*)(Bm + (size_t)(n0 + lr) * K + (k0 + lc));
        const float4 b1 = *(const float4*)(Bm + (size_t)(n0 + lr + 64) * K + (k0 + lc));

        __syncthreads();  // previous iteration's compute done before overwrite

        As[lc + 0][lr] = a0.x; As[lc + 1][lr] = a0.y;
        As[lc + 2][lr] = a0.z; As[lc + 3][lr] = a0.w;
        As[lc + 0][lr + 64] = a1.x; As[lc + 1][lr + 64] = a1.y;
        As[lc + 2][lr + 64] = a1.z; As[lc + 3][lr + 64] = a1.w;
        Bs[lc + 0][lr] = b0.x; Bs[lc + 1][lr] = b0.y;
        Bs[lc + 2][lr] = b0.z; Bs[lc + 3][lr] = b0.w;
        Bs[lc + 0][lr + 64] = b1.x; Bs[lc + 1][lr + 64] = b1.y;
        Bs[lc + 2][lr + 64] = b1.z; Bs[lc + 3][lr + 64] = b1.w;

        __syncthreads();

#pragma unroll
        for (int k = 0; k < 16; ++k) {   // ascending k within tile
            const float4 av0 = *(const float4*)&As[k][ty * 8];
            const float4 av1 = *(const float4*)&As[k][ty * 8 + 4];
            const float4 bv0 = *(const float4*)&Bs[k][tx * 8];
            const float4 bv1 = *(const float4*)&Bs[k][tx * 8 + 4];
            const float a[8] = {av0.x, av0.y, av0.z, av0.w, av1.x, av1.y, av1.z, av1.w};
            const float b[8] = {bv0.x, bv0.y, bv0.z, bv0.w, bv1.x, bv1.y, bv1.z, bv1.w};
#pragma unroll
            for (int i = 0; i < 8; ++i)
#pragma unroll
                for (int j = 0; j < 8; ++j)
                    acc[i][j] = __fadd_rn(acc[i][j], __fmul_rn(a[i], b[j]));
        }
    }

    // epilogue: + bias (after full k-chain), optional XLA tanh, float4 store
#pragma unroll
    for (int i = 0; i < 8; ++i) {
        const int m = m0 + ty * 8 + i;
        float v[8];
#pragma unroll
        for (int j = 0; j < 8; ++j) {
            const int n = n0 + tx * 8 + j;
            v[j] = __fadd_rn(acc[i][j], bias[n]);
            if (ACT) v[j] = xla_tanhf(v[j]);
        }
        float4* dst = (float4*)(C + (size_t)m * N + (n0 + tx * 8));
        dst[0] = make_float4(v[0], v[1], v[2], v[3]);
        dst[1] = make_float4(v[4], v[5], v[6], v[7]);
    }
}

// ---------------------------------------------------------------------------
// Sequential attractor scan — r7's PROVEN skeleton (128 threads, single et
// buffer, two barriers/step) + register double-buffered W prefetch.
// Thread e holds step i's W column in w0/w1 (128 VGPRs each); while the
// chain for step i runs, step i+1's 128 coalesced dword loads fill the
// other buffer. asm memory fences stop the compiler from sinking the loads
// into the chain (r9's failure mode: VGPR_Count=36, loads serialized).
// Chain is op-for-op the verified sequence: ascending d, non-fused
// __fmul_rn/__fadd_rn, one accumulator. et float4 LDS reads value-safe (r9).
// ---------------------------------------------------------------------------
__global__ __launch_bounds__(128, 1) void scan_kernel(const float* __restrict__ Wa,
                                                      const float* __restrict__ e0,
                                                      float* __restrict__ et_state,
                                                      float* __restrict__ out,
                                                      int i0, int CH) {
    const int b = blockIdx.x;
    const int e = threadIdx.x;  // 0..127

    __shared__ float et[128];

    if (i0 == 0) {
        const float v = e0[e];
        et[e] = v;
        out[(size_t)b * SS * ENC + e] = v;
    } else {
        et[e] = et_state[b * 128 + e];
    }
    __syncthreads();

    const int start = (i0 == 0) ? 1 : 0;
    const float* Wb = Wa + (size_t)b * CH * (ENC * ENC);

    float w0[128], w1[128];

    // prefetch first step's W column (coalesced across lanes per d)
    {
        const float* W = Wb + (size_t)start * (ENC * ENC);
#pragma unroll
        for (int d = 0; d < 128; ++d) w0[d] = W[d * ENC + e];
    }
    asm volatile("" ::: "memory");  // loads retire to regs before chain

// one scan step: chain on WBUF, out index (i0+STEP); r7 barrier structure
#define SCAN_STEP(WBUF, STEP)                                                 \
    {                                                                         \
        float sum = 0.f;                                                      \
        _Pragma("unroll")                                                     \
        for (int q = 0; q < 32; ++q) {                                        \
            const float4 t4 = *(const float4*)&et[q * 4];                     \
            sum = __fadd_rn(sum, __fmul_rn(t4.x, WBUF[q * 4 + 0]));           \
            sum = __fadd_rn(sum, __fmul_rn(t4.y, WBUF[q * 4 + 1]));           \
            sum = __fadd_rn(sum, __fmul_rn(t4.z, WBUF[q * 4 + 2]));           \
            sum = __fadd_rn(sum, __fmul_rn(t4.w, WBUF[q * 4 + 3]));           \
        }                                                                     \
        const float v = fminf(fmaxf(sum, -5.f), 5.f);                         \
        out[((size_t)b * SS + (i0 + (STEP))) * ENC + e] = v;                  \
        __syncthreads(); /* all chain reads of et done before overwrite */    \
        et[e] = v;                                                            \
        __syncthreads(); /* new et visible */                                 \
    }

    for (int ii = start; ii < CH; ii += 2) {
        // step ii on w0; prefetch ii+1 into w1
        if (ii + 1 < CH) {
            const float* W = Wb + (size_t)(ii + 1) * (ENC * ENC);
#pragma unroll
            for (int d = 0; d < 128; ++d) w1[d] = W[d * ENC + e];
        }
        asm volatile("" ::: "memory");
        SCAN_STEP(w0, ii)
        if (ii + 1 >= CH) break;

        // step ii+1 on w1; prefetch ii+2 into w0
        if (ii + 2 < CH) {
            const float* W = Wb + (size_t)(ii + 2) * (ENC * ENC);
#pragma unroll
            for (int d = 0; d < 128; ++d) w0[d] = W[d * ENC + e];
        }
        asm volatile("" ::: "memory");
        SCAN_STEP(w1, ii + 1)
    }
#undef SCAN_STEP

    et_state[b * 128 + e] = et[e];
}

// ---------------------------------------------------------------------------
extern "C" void kernel_launch(void* const* d_in, const int* in_sizes, int n_in,
                              void* d_out, int out_size, void* d_ws, size_t ws_size,
                              hipStream_t stream) {
    const float* A  = (const float*)d_in[0];  // (B,S,E)   = (8,512,128) fp32
    const float* W1 = (const float*)d_in[1];  // (H,E)     = (512,128)  fp32
    const float* b1 = (const float*)d_in[2];  // (H,)      fp32
    const float* W2 = (const float*)d_in[3];  // (ENC*ENC,H) = (16384,512) fp32
    const float* b2 = (const float*)d_in[4];  // (ENC*ENC,) fp32
    const float* e0 = (const float*)d_in[5];  // (1,ENC)   fp32
    float* out = (float*)d_out;               // (B,S,ENC) fp32

    // Pick the largest chunk CH (steps) whose fp32 workspace fits ws_size.
    // ws layout: [et_state 4KB][hidden_c Mc*512 f32][Wa_c Mc*16384 f32], Mc=8*CH
    int CH = 16;  // minimum (Mc=128, one M-tile); needs ~8.7 MB
    for (int c = 512; c >= 16; c >>= 1) {
        const size_t Mc = (size_t)BB * c;
        const size_t need = 4096 + Mc * HH * sizeof(float) +
                            Mc * (size_t)(ENC * ENC) * sizeof(float);
        if (need <= ws_size) { CH = c; break; }
    }
    const int Mc = BB * CH;
    int chsh = 0;
    while ((1 << chsh) < CH) ++chsh;
    const int chm1 = CH - 1;

    float* et_state = (float*)d_ws;
    float* hidden   = (float*)((char*)d_ws + 4096);
    float* Wa       = hidden + (size_t)Mc * HH;

    for (int i0 = 0; i0 < SS; i0 += CH) {
        // GEMM1: hidden_c = tanh(A[chunk rows] @ W1^T + b1)  [Mc x 512, K=128]
        dim3 g1(HH / 128, Mc / 128);
        gemm_nt<1, 1><<<g1, 256, 0, stream>>>(A, W1, b1, hidden, HH, EE,
                                              chm1, chsh, i0);
        // GEMM2: Wa_c = hidden_c @ W2^T + b2   [Mc x 16384, K=512]
        dim3 g2((ENC * ENC) / 128, Mc / 128);
        gemm_nt<0, 0><<<g2, 256, 0, stream>>>(hidden, W2, b2, Wa, ENC * ENC, HH,
                                              0, 0, 0);
        // scan this chunk (one workgroup per batch; fp32 state in ws)
        scan_kernel<<<BB, 128, 0, stream>>>(Wa, e0, et_state, out, i0, CH);
    }
}

// Round 12
// 1980.847 us; speedup vs baseline: 1.4674x; 1.0318x over previous
//
#include <hip/hip_runtime.h>
#include <cstddef>

// Problem constants (reference: B=8, S=512, E=128, H=512, ENC=128)
#define BB 8
#define SS 512
#define EE 128
#define HH 512
#define ENC 128

// ---------------------------------------------------------------------------
// Bit-exact emulation of XLA CPU's EmitTanh (verified bitwise r6/r7/r9/r11).
// All ops rn, NON-fused. __f*_rn intrinsics block compiler contraction.
// NOTE (r8): packed v_pk_* fp32 is NOT bit-identical on gfx950 — scalar only.
// ---------------------------------------------------------------------------
__device__ __forceinline__ float xla_tanhf(float x) {
    const float cx = fminf(fmaxf(x, -9.0f), 9.0f);
    const float x2 = __fmul_rn(cx, cx);
    float p = -2.76076847742355e-16f;
    p = __fadd_rn(__fmul_rn(p, x2), 2.00018790482477e-13f);
    p = __fadd_rn(__fmul_rn(p, x2), -8.60467152213735e-11f);
    p = __fadd_rn(__fmul_rn(p, x2), 5.12229709037114e-08f);
    p = __fadd_rn(__fmul_rn(p, x2), 1.48572235717979e-05f);
    p = __fadd_rn(__fmul_rn(p, x2), 6.37261928875436e-04f);
    p = __fadd_rn(__fmul_rn(p, x2), 4.89352455891786e-03f);
    const float num = __fmul_rn(cx, p);
    float q = 1.19825839466702e-06f;
    q = __fadd_rn(__fmul_rn(q, x2), 1.18534705686654e-04f);
    q = __fadd_rn(__fmul_rn(q, x2), 2.26843463243900e-03f);
    q = __fadd_rn(__fmul_rn(q, x2), 4.89352518554385e-03f);
    const float r = __fdiv_rn(num, q);
    return (fabsf(x) < 0.0004f) ? x : r;
}

// Map a packed chunk-row m -> global action row:
//   b = m >> chsh (CH = chm1+1), global row = b*SS + i0 + (m & chm1)
__device__ __forceinline__ int arow_map(int m, int chm1, int chsh, int i0) {
    return ((m >> chsh) * SS) + i0 + (m & chm1);
}

// Async global->LDS DMA, 16 B per lane (wave-uniform LDS base + lane*16).
// Tracked by vmcnt; __syncthreads()'s vmcnt(0) drain completes it.
__device__ __forceinline__ void dma_lds16(const float* g, float* l) {
    __builtin_amdgcn_global_load_lds(
        (const __attribute__((address_space(1))) void*)g,
        (__attribute__((address_space(3))) void*)l,
        16, 0, 0);
}

// ---------------------------------------------------------------------------
// Tiled GEMM, bitwise-preserving XLA-CPU dot semantics (VERIFIED r6/r7/r9/r11
// — scalar v_mul/v_add only; r8's packed ops regressed). At the scalar-VALU
// floor for GEMM2 (~874 us). DO NOT TOUCH.
// ---------------------------------------------------------------------------
template <int ACT, int MAPROW>
__global__ __launch_bounds__(256) void gemm_nt(const float* __restrict__ A,
                                               const float* __restrict__ Bm,
                                               const float* __restrict__ bias,
                                               float* __restrict__ C,
                                               int N, int K,
                                               int chm1, int chsh, int i0) {
    __shared__ float As[16][128];
    __shared__ float Bs[16][128];

    const int tid = threadIdx.x;
    const int tx = tid & 15;   // n-direction (8 cols each)
    const int ty = tid >> 4;   // m-direction (8 rows each)
    const int n0 = blockIdx.x * 128;
    const int m0 = blockIdx.y * 128;

    const int lr = tid >> 2;          // 0..63 (row within tile)
    const int lc = (tid & 3) << 2;    // 0,4,8,12 (col within K-tile)

    const int ga0 = MAPROW ? arow_map(m0 + lr, chm1, chsh, i0) : (m0 + lr);
    const int ga1 = MAPROW ? arow_map(m0 + lr + 64, chm1, chsh, i0) : (m0 + lr + 64);

    float acc[8][8];
#pragma unroll
    for (int i = 0; i < 8; ++i)
#pragma unroll
        for (int j = 0; j < 8; ++j) acc[i][j] = 0.f;

    for (int k0 = 0; k0 < K; k0 += 16) {
        const float4 a0 = *(const float4*)(A + (size_t)ga0 * K + (k0 + lc));
        const float4 a1 = *(const float4*)(A + (size_t)ga1 * K + (k0 + lc));
        const float4 b0 = *(const float4*)(Bm + (size_t)(n0 + lr) * K + (k0 + lc));
        const float4 b1 = *(const float4*)(Bm + (size_t)(n0 + lr + 64) * K + (k0 + lc));

        __syncthreads();  // previous iteration's compute done before overwrite

        As[lc + 0][lr] = a0.x; As[lc + 1][lr] = a0.y;
        As[lc + 2][lr] = a0.z; As[lc + 3][lr] = a0.w;
        As[lc + 0][lr + 64] = a1.x; As[lc + 1][lr + 64] = a1.y;
        As[lc + 2][lr + 64] = a1.z; As[lc + 3][lr + 64] = a1.w;
        Bs[lc + 0][lr] = b0.x; Bs[lc + 1][lr] = b0.y;
        Bs[lc + 2][lr] = b0.z; Bs[lc + 3][lr] = b0.w;
        Bs[lc + 0][lr + 64] = b1.x; Bs[lc + 1][lr + 64] = b1.y;
        Bs[lc + 2][lr + 64] = b1.z; Bs[lc + 3][lr + 64] = b1.w;

        __syncthreads();

#pragma unroll
        for (int k = 0; k < 16; ++k) {   // ascending k within tile
            const float4 av0 = *(const float4*)&As[k][ty * 8];
            const float4 av1 = *(const float4*)&As[k][ty * 8 + 4];
            const float4 bv0 = *(const float4*)&Bs[k][tx * 8];
            const float4 bv1 = *(const float4*)&Bs[k][tx * 8 + 4];
            const float a[8] = {av0.x, av0.y, av0.z, av0.w, av1.x, av1.y, av1.z, av1.w};
            const float b[8] = {bv0.x, bv0.y, bv0.z, bv0.w, bv1.x, bv1.y, bv1.z, bv1.w};
#pragma unroll
            for (int i = 0; i < 8; ++i)
#pragma unroll
                for (int j = 0; j < 8; ++j)
                    acc[i][j] = __fadd_rn(acc[i][j], __fmul_rn(a[i], b[j]));
        }
    }

    // epilogue: + bias (after full k-chain), optional XLA tanh, float4 store
#pragma unroll
    for (int i = 0; i < 8; ++i) {
        const int m = m0 + ty * 8 + i;
        float v[8];
#pragma unroll
        for (int j = 0; j < 8; ++j) {
            const int n = n0 + tx * 8 + j;
            v[j] = __fadd_rn(acc[i][j], bias[n]);
            if (ACT) v[j] = xla_tanhf(v[j]);
        }
        float4* dst = (float4*)(C + (size_t)m * N + (n0 + tx * 8));
        dst[0] = make_float4(v[0], v[1], v[2], v[3]);
        dst[1] = make_float4(v[4], v[5], v[6], v[7]);
    }
}

// ---------------------------------------------------------------------------
// Sequential attractor scan — global_load_lds quarter-tile pipeline.
// One block per batch, 128 threads (2 waves), thread t = output coord e.
// Each step's 64 KB W is streamed as four 16 KB quarter-tiles (32 d-rows).
// While the chain consumes tile tau from LDS buf[cur], tile tau+1 is DMA'd
// into buf[cur^1] (async, zero VGPR cost). The per-quarter __syncthreads()
// drains vmcnt(0) (compiler-guaranteed), completing the DMA and protecting
// buffer reuse — no manual waitcnt.
// Chain is op-for-op the verified sequence: strictly ascending d across
// quarters, ONE accumulator, non-fused __fmul_rn/__fadd_rn (bitwise
// contract). et ping-pongs (write et[s^1] during q3 while readers use
// et[s]) so the q3 barrier also publishes et — 4 barriers/step.
// W LDS reads: bank = t%32, 2 lanes/bank = conflict-free (m136);
// et reads are b128 broadcasts. LDS total 33 KB.
// ---------------------------------------------------------------------------
__global__ __launch_bounds__(128, 1) void scan_kernel(const float* __restrict__ Wa,
                                                      const float* __restrict__ e0,
                                                      float* __restrict__ et_state,
                                                      float* __restrict__ out,
                                                      int i0, int CH) {
    const int b = blockIdx.x;
    const int t = threadIdx.x;   // 0..127
    const int wave = t >> 6;     // 0..1
    const int lane = t & 63;

    __shared__ float Wq[2][4096];   // 2 x 16 KB quarter-tile buffers
    __shared__ float et[2][128];    // ping-pong state

    int s = 0;
    if (i0 == 0) {
        const float v = e0[t];
        et[0][t] = v;
        out[(size_t)b * SS * ENC + t] = v;
    } else {
        et[0][t] = et_state[b * 128 + t];
    }

    const int start = (i0 == 0) ? 1 : 0;
    const float* Wb = Wa + (size_t)b * CH * (ENC * ENC);
    const int nq_total = (CH - start) * 4;   // total quarter-tiles this launch

    // preload tile 0 (step `start`, quarter 0) into buf 0
    {
        const float* src = Wb + (size_t)start * (ENC * ENC);
#pragma unroll
        for (int u = 0; u < 8; ++u) {
            const int off = (u * 2 + wave) * 256;   // floats; 1 KB per instr
            dma_lds16(src + off + lane * 4, &Wq[0][off]);
        }
    }
    __syncthreads();   // buf0 DMA complete (vmcnt drain); et visible

    int cur = 0;
    for (int ii = start; ii < CH; ++ii) {
        float sum = 0.f;   // ONE accumulator, ascending d across all quarters
#pragma unroll
        for (int q = 0; q < 4; ++q) {
            // issue async DMA for the next quarter-tile into the other buffer
            const int tau = (ii - start) * 4 + q;
            if (tau + 1 < nq_total) {
                const int nxt = tau + 1;
                const float* src = Wb + (size_t)(start + (nxt >> 2)) * (ENC * ENC)
                                      + (nxt & 3) * 4096;
#pragma unroll
                for (int u = 0; u < 8; ++u) {
                    const int off = (u * 2 + wave) * 256;
                    dma_lds16(src + off + lane * 4, &Wq[cur ^ 1][off]);
                }
            }
            // chain quarter q: d = 32q .. 32q+31 (LDS row dq = d - 32q)
#pragma unroll
            for (int dq = 0; dq < 8; ++dq) {
                const float4 t4 = *(const float4*)&et[s][q * 32 + dq * 4];
                sum = __fadd_rn(sum, __fmul_rn(t4.x, Wq[cur][(dq * 4 + 0) * ENC + t]));
                sum = __fadd_rn(sum, __fmul_rn(t4.y, Wq[cur][(dq * 4 + 1) * ENC + t]));
                sum = __fadd_rn(sum, __fmul_rn(t4.z, Wq[cur][(dq * 4 + 2) * ENC + t]));
                sum = __fadd_rn(sum, __fmul_rn(t4.w, Wq[cur][(dq * 4 + 3) * ENC + t]));
            }
            if (q == 3) {
                const float v = fminf(fmaxf(sum, -5.f), 5.f);  // jnp.clip
                out[((size_t)b * SS + (i0 + ii)) * ENC + t] = v;
                et[s ^ 1][t] = v;   // readers this step use et[s] — no conflict
            }
            __syncthreads();  // DMA drained; buf[cur] reads done; q3: et published
            cur ^= 1;
        }
        s ^= 1;
    }
    et_state[b * 128 + t] = et[s][t];
}

// ---------------------------------------------------------------------------
extern "C" void kernel_launch(void* const* d_in, const int* in_sizes, int n_in,
                              void* d_out, int out_size, void* d_ws, size_t ws_size,
                              hipStream_t stream) {
    const float* A  = (const float*)d_in[0];  // (B,S,E)   = (8,512,128) fp32
    const float* W1 = (const float*)d_in[1];  // (H,E)     = (512,128)  fp32
    const float* b1 = (const float*)d_in[2];  // (H,)      fp32
    const float* W2 = (const float*)d_in[3];  // (ENC*ENC,H) = (16384,512) fp32
    const float* b2 = (const float*)d_in[4];  // (ENC*ENC,) fp32
    const float* e0 = (const float*)d_in[5];  // (1,ENC)   fp32
    float* out = (float*)d_out;               // (B,S,ENC) fp32

    // Pick the largest chunk CH (steps) whose fp32 workspace fits ws_size.
    // ws layout: [et_state 4KB][hidden_c Mc*512 f32][Wa_c Mc*16384 f32], Mc=8*CH
    int CH = 16;  // minimum (Mc=128, one M-tile); needs ~8.7 MB
    for (int c = 512; c >= 16; c >>= 1) {
        const size_t Mc = (size_t)BB * c;
        const size_t need = 4096 + Mc * HH * sizeof(float) +
                            Mc * (size_t)(ENC * ENC) * sizeof(float);
        if (need <= ws_size) { CH = c; break; }
    }
    const int Mc = BB * CH;
    int chsh = 0;
    while ((1 << chsh) < CH) ++chsh;
    const int chm1 = CH - 1;

    float* et_state = (float*)d_ws;
    float* hidden   = (float*)((char*)d_ws + 4096);
    float* Wa       = hidden + (size_t)Mc * HH;

    for (int i0 = 0; i0 < SS; i0 += CH) {
        // GEMM1: hidden_c = tanh(A[chunk rows] @ W1^T + b1)  [Mc x 512, K=128]
        dim3 g1(HH / 128, Mc / 128);
        gemm_nt<1, 1><<<g1, 256, 0, stream>>>(A, W1, b1, hidden, HH, EE,
                                              chm1, chsh, i0);
        // GEMM2: Wa_c = hidden_c @ W2^T + b2   [Mc x 16384, K=512]
        dim3 g2((ENC * ENC) / 128, Mc / 128);
        gemm_nt<0, 0><<<g2, 256, 0, stream>>>(hidden, W2, b2, Wa, ENC * ENC, HH,
                                              0, 0, 0);
        // scan this chunk (one workgroup per batch; fp32 state in ws)
        scan_kernel<<<BB, 128, 0, stream>>>(Wa, e0, et_state, out, i0, CH);
    }
}

// Round 13
// 1803.400 us; speedup vs baseline: 1.6118x; 1.0984x over previous
//
#include <hip/hip_runtime.h>
#include <cstddef>

// Problem constants (reference: B=8, S=512, E=128, H=512, ENC=128)
#define BB 8
#define SS 512
#define EE 128
#define HH 512
#define ENC 128

// ---------------------------------------------------------------------------
// Bit-exact emulation of XLA CPU's EmitTanh (verified bitwise r6/r7/r9/r11/r12).
// All ops rn, NON-fused. __f*_rn intrinsics block compiler contraction.
// NOTE (r8): packed v_pk_* fp32 is NOT bit-identical on gfx950 — scalar only.
// ---------------------------------------------------------------------------
__device__ __forceinline__ float xla_tanhf(float x) {
    const float cx = fminf(fmaxf(x, -9.0f), 9.0f);
    const float x2 = __fmul_rn(cx, cx);
    float p = -2.76076847742355e-16f;
    p = __fadd_rn(__fmul_rn(p, x2), 2.00018790482477e-13f);
    p = __fadd_rn(__fmul_rn(p, x2), -8.60467152213735e-11f);
    p = __fadd_rn(__fmul_rn(p, x2), 5.12229709037114e-08f);
    p = __fadd_rn(__fmul_rn(p, x2), 1.48572235717979e-05f);
    p = __fadd_rn(__fmul_rn(p, x2), 6.37261928875436e-04f);
    p = __fadd_rn(__fmul_rn(p, x2), 4.89352455891786e-03f);
    const float num = __fmul_rn(cx, p);
    float q = 1.19825839466702e-06f;
    q = __fadd_rn(__fmul_rn(q, x2), 1.18534705686654e-04f);
    q = __fadd_rn(__fmul_rn(q, x2), 2.26843463243900e-03f);
    q = __fadd_rn(__fmul_rn(q, x2), 4.89352518554385e-03f);
    const float r = __fdiv_rn(num, q);
    return (fabsf(x) < 0.0004f) ? x : r;
}

// Map a packed chunk-row m -> global action row:
//   b = m >> chsh (CH = chm1+1), global row = b*SS + i0 + (m & chm1)
__device__ __forceinline__ int arow_map(int m, int chm1, int chsh, int i0) {
    return ((m >> chsh) * SS) + i0 + (m & chm1);
}

// ---------------------------------------------------------------------------
// Tiled GEMM, bitwise-preserving XLA-CPU dot semantics (VERIFIED r6..r12 —
// scalar v_mul/v_add only; r8's packed ops regressed). Measured at the
// scalar-VALU floor for GEMM2 (~437 us/chunk). DO NOT TOUCH.
// ---------------------------------------------------------------------------
template <int ACT, int MAPROW>
__global__ __launch_bounds__(256) void gemm_nt(const float* __restrict__ A,
                                               const float* __restrict__ Bm,
                                               const float* __restrict__ bias,
                                               float* __restrict__ C,
                                               int N, int K,
                                               int chm1, int chsh, int i0) {
    __shared__ float As[16][128];
    __shared__ float Bs[16][128];

    const int tid = threadIdx.x;
    const int tx = tid & 15;   // n-direction (8 cols each)
    const int ty = tid >> 4;   // m-direction (8 rows each)
    const int n0 = blockIdx.x * 128;
    const int m0 = blockIdx.y * 128;

    const int lr = tid >> 2;          // 0..63 (row within tile)
    const int lc = (tid & 3) << 2;    // 0,4,8,12 (col within K-tile)

    const int ga0 = MAPROW ? arow_map(m0 + lr, chm1, chsh, i0) : (m0 + lr);
    const int ga1 = MAPROW ? arow_map(m0 + lr + 64, chm1, chsh, i0) : (m0 + lr + 64);

    float acc[8][8];
#pragma unroll
    for (int i = 0; i < 8; ++i)
#pragma unroll
        for (int j = 0; j < 8; ++j) acc[i][j] = 0.f;

    for (int k0 = 0; k0 < K; k0 += 16) {
        const float4 a0 = *(const float4*)(A + (size_t)ga0 * K + (k0 + lc));
        const float4 a1 = *(const float4*)(A + (size_t)ga1 * K + (k0 + lc));
        const float4 b0 = *(const float4*)(Bm + (size_t)(n0 + lr) * K + (k0 + lc));
        const float4 b1 = *(const float4*)(Bm + (size_t)(n0 + lr + 64) * K + (k0 + lc));

        __syncthreads();  // previous iteration's compute done before overwrite

        As[lc + 0][lr] = a0.x; As[lc + 1][lr] = a0.y;
        As[lc + 2][lr] = a0.z; As[lc + 3][lr] = a0.w;
        As[lc + 0][lr + 64] = a1.x; As[lc + 1][lr + 64] = a1.y;
        As[lc + 2][lr + 64] = a1.z; As[lc + 3][lr + 64] = a1.w;
        Bs[lc + 0][lr] = b0.x; Bs[lc + 1][lr] = b0.y;
        Bs[lc + 2][lr] = b0.z; Bs[lc + 3][lr] = b0.w;
        Bs[lc + 0][lr + 64] = b1.x; Bs[lc + 1][lr + 64] = b1.y;
        Bs[lc + 2][lr + 64] = b1.z; Bs[lc + 3][lr + 64] = b1.w;

        __syncthreads();

#pragma unroll
        for (int k = 0; k < 16; ++k) {   // ascending k within tile
            const float4 av0 = *(const float4*)&As[k][ty * 8];
            const float4 av1 = *(const float4*)&As[k][ty * 8 + 4];
            const float4 bv0 = *(const float4*)&Bs[k][tx * 8];
            const float4 bv1 = *(const float4*)&Bs[k][tx * 8 + 4];
            const float a[8] = {av0.x, av0.y, av0.z, av0.w, av1.x, av1.y, av1.z, av1.w};
            const float b[8] = {bv0.x, bv0.y, bv0.z, bv0.w, bv1.x, bv1.y, bv1.z, bv1.w};
#pragma unroll
            for (int i = 0; i < 8; ++i)
#pragma unroll
                for (int j = 0; j < 8; ++j)
                    acc[i][j] = __fadd_rn(acc[i][j], __fmul_rn(a[i], b[j]));
        }
    }

    // epilogue: + bias (after full k-chain), optional XLA tanh, float4 store
#pragma unroll
    for (int i = 0; i < 8; ++i) {
        const int m = m0 + ty * 8 + i;
        float v[8];
#pragma unroll
        for (int j = 0; j < 8; ++j) {
            const int n = n0 + tx * 8 + j;
            v[j] = __fadd_rn(acc[i][j], bias[n]);
            if (ACT) v[j] = xla_tanhf(v[j]);
        }
        float4* dst = (float4*)(C + (size_t)m * N + (n0 + tx * 8));
        dst[0] = make_float4(v[0], v[1], v[2], v[3]);
        dst[1] = make_float4(v[4], v[5], v[6], v[7]);
    }
}

// ---------------------------------------------------------------------------
// Sequential attractor scan — quarter-grain register prefetch pipeline.
// One block per batch, 128 threads (2 waves), thread e = output coord.
// Four 32-float register buffers; at quarter gq we issue the 32 coalesced
// loads for quarter gq+3 (buffer (gq+3)&3 = (gq+3)%4), fence, then run the
// chain on buffer gq&3. Prefetch distance = 3 quarters (~900 cyc of chain)
// covers L3/HBM latency. 128 buffer VGPRs (+~45 misc) fits the 256 budget —
// fixes r11's 252-VGPR partial sinking. Only 2 barriers/step (r7's proven
// et publish); no intra-step barriers, so no per-quarter vmcnt(0) drains
// (r12's structural stall).
// Chain is op-for-op the verified sequence: ONE accumulator, strictly
// ascending d, non-fused __fmul_rn/__fadd_rn (bitwise contract). Register
// staging + et float4 LDS reads proven value-safe (r9/r11).
// ---------------------------------------------------------------------------
__global__ __launch_bounds__(128, 1) void scan_kernel(const float* __restrict__ Wa,
                                                      const float* __restrict__ e0,
                                                      float* __restrict__ et_state,
                                                      float* __restrict__ out,
                                                      int i0, int CH) {
    const int b = blockIdx.x;
    const int e = threadIdx.x;  // 0..127

    __shared__ float et[128];

    if (i0 == 0) {
        const float v = e0[e];
        et[e] = v;
        out[(size_t)b * SS * ENC + e] = v;
    } else {
        et[e] = et_state[b * 128 + e];
    }
    __syncthreads();

    const int start = (i0 == 0) ? 1 : 0;
    const float* Wb = Wa + (size_t)b * CH * (ENC * ENC);
    const int nq = (CH - start) * 4;   // total quarter-tiles this launch

    float w[4][32];   // 4 quarter buffers, 32 VGPRs each

    // preload quarters 0,1,2 of step `start`
    {
        const float* S = Wb + (size_t)start * (ENC * ENC) + e;
#pragma unroll
        for (int d = 0; d < 32; ++d) w[0][d] = S[d * ENC];
#pragma unroll
        for (int d = 0; d < 32; ++d) w[1][d] = S[(32 + d) * ENC];
#pragma unroll
        for (int d = 0; d < 32; ++d) w[2][d] = S[(64 + d) * ENC];
    }
    asm volatile("" ::: "memory");  // loads pinned before first chain

    for (int ii = start; ii < CH; ++ii) {
        float sum = 0.f;   // ONE accumulator, ascending d across all quarters
#pragma unroll
        for (int q = 0; q < 4; ++q) {
            // issue prefetch for quarter gq+3 into buffer (q+3)&3
            const int pf = (ii - start) * 4 + q + 3;
            if (pf < nq) {
                const float* src = Wb + (size_t)(start + (pf >> 2)) * (ENC * ENC)
                                      + (size_t)(pf & 3) * 32 * ENC + e;
#pragma unroll
                for (int d = 0; d < 32; ++d) w[(q + 3) & 3][d] = src[d * ENC];
            }
            asm volatile("" ::: "memory");
            // consume quarter q (buffer q): d = 32q .. 32q+31, ascending
#pragma unroll
            for (int dq = 0; dq < 8; ++dq) {
                const float4 t4 = *(const float4*)&et[q * 32 + dq * 4];
                sum = __fadd_rn(sum, __fmul_rn(t4.x, w[q][dq * 4 + 0]));
                sum = __fadd_rn(sum, __fmul_rn(t4.y, w[q][dq * 4 + 1]));
                sum = __fadd_rn(sum, __fmul_rn(t4.z, w[q][dq * 4 + 2]));
                sum = __fadd_rn(sum, __fmul_rn(t4.w, w[q][dq * 4 + 3]));
            }
        }
        const float v = fminf(fmaxf(sum, -5.f), 5.f);  // jnp.clip
        out[((size_t)b * SS + (i0 + ii)) * ENC + e] = v;
        __syncthreads();   // all chain reads of et done before overwrite
        et[e] = v;
        __syncthreads();   // new et visible
    }
    et_state[b * 128 + e] = et[e];
}

// ---------------------------------------------------------------------------
extern "C" void kernel_launch(void* const* d_in, const int* in_sizes, int n_in,
                              void* d_out, int out_size, void* d_ws, size_t ws_size,
                              hipStream_t stream) {
    const float* A  = (const float*)d_in[0];  // (B,S,E)   = (8,512,128) fp32
    const float* W1 = (const float*)d_in[1];  // (H,E)     = (512,128)  fp32
    const float* b1 = (const float*)d_in[2];  // (H,)      fp32
    const float* W2 = (const float*)d_in[3];  // (ENC*ENC,H) = (16384,512) fp32
    const float* b2 = (const float*)d_in[4];  // (ENC*ENC,) fp32
    const float* e0 = (const float*)d_in[5];  // (1,ENC)   fp32
    float* out = (float*)d_out;               // (B,S,ENC) fp32

    // Pick the largest chunk CH (steps) whose fp32 workspace fits ws_size.
    // ws layout: [et_state 4KB][hidden_c Mc*512 f32][Wa_c Mc*16384 f32], Mc=8*CH
    int CH = 16;  // minimum (Mc=128, one M-tile); needs ~8.7 MB
    for (int c = 512; c >= 16; c >>= 1) {
        const size_t Mc = (size_t)BB * c;
        const size_t need = 4096 + Mc * HH * sizeof(float) +
                            Mc * (size_t)(ENC * ENC) * sizeof(float);
        if (need <= ws_size) { CH = c; break; }
    }
    const int Mc = BB * CH;
    int chsh = 0;
    while ((1 << chsh) < CH) ++chsh;
    const int chm1 = CH - 1;

    float* et_state = (float*)d_ws;
    float* hidden   = (float*)((char*)d_ws + 4096);
    float* Wa       = hidden + (size_t)Mc * HH;

    for (int i0 = 0; i0 < SS; i0 += CH) {
        // GEMM1: hidden_c = tanh(A[chunk rows] @ W1^T + b1)  [Mc x 512, K=128]
        dim3 g1(HH / 128, Mc / 128);
        gemm_nt<1, 1><<<g1, 256, 0, stream>>>(A, W1, b1, hidden, HH, EE,
                                              chm1, chsh, i0);
        // GEMM2: Wa_c = hidden_c @ W2^T + b2   [Mc x 16384, K=512]
        dim3 g2((ENC * ENC) / 128, Mc / 128);
        gemm_nt<0, 0><<<g2, 256, 0, stream>>>(hidden, W2, b2, Wa, ENC * ENC, HH,
                                              0, 0, 0);
        // scan this chunk (one workgroup per batch; fp32 state in ws)
        scan_kernel<<<BB, 128, 0, stream>>>(Wa, e0, et_state, out, i0, CH);
    }
}